// Round 4
// baseline (654.021 us; speedup 1.0000x reference)
//
#include <hip/hip_runtime.h>

typedef __attribute__((ext_vector_type(8))) short short8;
typedef __attribute__((ext_vector_type(8))) int int8v;
typedef __attribute__((ext_vector_type(16))) float floatx16;
typedef __attribute__((ext_vector_type(4))) unsigned int uint4v;
typedef unsigned short ushort_t;
typedef unsigned int uint_t;
typedef unsigned char uchar_t;

#define NA   256
#define CIN  128
#define HFD  320
#define FMPX (HFD*HFD)
#define IMGD 1280

// ws layout (bytes):
//   [0, 1MB)              logits f32 (NA*1024)
//   [1MB, +294912)        w1b fp8  [tap][g][nt][c][lane64][32B]  (coalesced B-frag layout), scaled x64
//   [+294912, +311296)    w2r bf16 [32 krow][256 oc]
//   [2MB, 2MB+13107200)   fmT fp8  [320 y][320 x][128 c]
#define W1R_BYTE_OFF (1u<<20)
#define W2R_BYTE_OFF ((1u<<20) + 9*256*128)
#define FMT_BYTE_OFF (2u<<20)

#define SAPL_M 5456   // A sub-plane stride: 340 cells*16 + 16 pad (1364 dw ≡ 20 mod 32 banks
                      // -> 8 planes hit 8 disjoint 4-bank groups on staging writes)
#define PSTR_Q 4112   // bytes per oc-octet plane of s_h: 8*32*16 + 16 pad

union V32 { int8v v; uint4v q[2]; };

__device__ __forceinline__ ushort_t f2bf(float v) {
    uint_t u = __float_as_uint(v);
    return (ushort_t)((u + 0x8000u) >> 16);
}
__device__ __forceinline__ uchar_t f2fp8(float v) {
    int r = __builtin_amdgcn_cvt_pk_fp8_f32(v, 0.0f, 0, false);
    return (uchar_t)(r & 0xff);
}

__global__ __launch_bounds__(256) void prep_misc(
    const float* __restrict__ W1, const float* __restrict__ W2,
    float* __restrict__ logits, float* __restrict__ out,
    uchar_t* __restrict__ w1b, ushort_t* __restrict__ w2r)
{
    const int b = blockIdx.x, t = threadIdx.x;
    if (b < 1024) {
        logits[b * 256 + t] = 0.0f;
    } else if (b < 1024 + 128) {
        int e = (b - 1024) * 256 + t;
        int oc = e >> 7, cin = e & 127;
        int g = oc >> 6, nt = (oc >> 5) & 1, lv = oc & 31;
        int c = cin >> 6, kh = (cin >> 5) & 1, j = cin & 31;
        #pragma unroll
        for (int tap = 0; tap < 9; ++tap) {
            int idx = (((((tap * 4 + g) * 2 + nt) * 2 + c) * 64) + kh * 32 + lv) * 32 + j;
            w1b[idx] = f2fp8(W1[(oc * 128 + cin) * 9 + tap] * 64.0f);
        }
    } else {
        #pragma unroll
        for (int i = 0; i < 32; ++i) {
            int e = i * 256 + t;
            int nrow = e >> 8, oc = e & 255;
            w2r[nrow * 256 + oc] = f2bf(nrow < 9 ? W2[oc * 9 + nrow] : 0.0f);
        }
        if (t == 0) out[0] = 0.0f;
    }
}

// fm f32 [c][y][x] -> fmT fp8 [y][x][c]
__global__ __launch_bounds__(256) void prep_transpose(
    const float* __restrict__ fm, uchar_t* __restrict__ fmT)
{
    __shared__ uchar_t s[32 * 144];
    const int t = threadIdx.x;
    const int y = blockIdx.y, x0b = blockIdx.x * 32;
    #pragma unroll
    for (int i = 0; i < 16; ++i) {
        int e = t + 256 * i;
        int c = e >> 5, xo = e & 31;
        s[xo * 144 + c] = f2fp8(fm[(size_t)c * FMPX + y * HFD + x0b + xo]);
    }
    __syncthreads();
    {
        int xo = t >> 3, cg = t & 7;
        uint4v v = *(const uint4v*)&s[xo * 144 + cg * 16];
        *(uint4v*)&fmT[((size_t)(y * HFD + x0b + xo)) * 128 + cg * 16] = v;
    }
}

// Block = (anchor, 8-row quarter, 64-oc group); grid 4096, XCD-swizzled.
// R4 structure: ALL 128 cin staged once (8 sub-planes, 43.6 KB) -> single barrier, then
// 18 uninterrupted MFMA steps. B prefetch distance 2 via 3 rotating statically-named
// buffers in a 6-step unrolled body (#pragma unroll 1 outer): buffer WAR deps bound the
// scheduler window to 48 B-regs -- the R1/R2 hoist-spill cannot recur (R1: 450 MB scratch,
// R2: 253 MB; R3 rolled+1-deep: clean but MfmaUtil stuck 27% on vmcnt exposure).
// Accumulation order (c, kx, ky) preserved exactly: s in [0,18), c=s/9, r=s%9, kx=r/3, ky=r%3.
// B operand from L2 (w1b pre-permuted: one coalesced 2048-B wave read per frag).
__global__ __launch_bounds__(256, 3) void conv_mfma_kernel(
    const int* __restrict__ anchors, const uchar_t* __restrict__ fmT,
    const uchar_t* __restrict__ w1b, const ushort_t* __restrict__ w2r,
    const float* __restrict__ b1, float* __restrict__ logits)
{
    const int id   = blockIdx.x;
    const int xcd  = id & 7, sid = id >> 3;
    const int n    = xcd * 32 + (sid >> 4);
    const int rem  = sid & 15;
    const int q    = rem >> 2;
    const int g    = rem & 3;

    const int t    = threadIdx.x;
    const int w    = t >> 6;
    const int lane = t & 63;
    const int l31  = lane & 31;
    const int kh   = lane >> 5;

    const int x0 = anchors[n * 4 + 0];
    const int y0 = anchors[n * 4 + 2];
    const int r0 = q * 8;

    __shared__ __align__(16) char smem[8 * SAPL_M];   // 43648 B: s_a (8 planes) / s_h union
    __shared__ float s_log[10 * 32];
    char* s_a = smem;

    floatx16 acc[2][2];
    #pragma unroll
    for (int mt = 0; mt < 2; ++mt)
        #pragma unroll
        for (int nt = 0; nt < 2; ++nt)
            #pragma unroll
            for (int r = 0; r < 16; ++r) acc[mt][nt][r] = 0.0f;

    // B-fragment loader: tap in [0,9), cc = cin chunk
    auto loadB = [&](int tap, int cc, V32* b) {
        #pragma unroll
        for (int nt = 0; nt < 2; ++nt) {
            const uchar_t* bp = w1b + ((((tap * 4 + g) * 2 + nt) * 2 + cc) << 11) + lane * 32;
            b[nt].q[0] = *(const uint4v*)(bp);
            b[nt].q[1] = *(const uint4v*)(bp + 16);
        }
    };

    V32 b0[2], b1v[2], b2[2];
    loadB(0, 0, b0);    // s=0: kx0 ky0 -> tap 0, c 0
    loadB(3, 0, b1v);   // s=1: kx0 ky1 -> tap 3, c 0

    // zero col pads: 8 planes x 10 rows x 2 cols = 160 units
    if (t < 160) {
        int p = t & 7, k = t >> 3;
        int pr = k >> 1, col = (k & 1) * 33;
        uint4v z = {0u, 0u, 0u, 0u};
        *(uint4v*)(s_a + p * SAPL_M + (pr * 34 + col) * 16) = z;
    }
    // ---- stage A: all 128 cin. 10 rows x 32 cols x 8 subs = 2560 uint4 units ----
    // thread t: p = t&7 fixed; 8 consecutive lanes cover one (y,x)'s 128 B -> coalesced.
    #pragma unroll
    for (int j = 0; j < 10; ++j) {
        int u = t + 256 * j;
        int p = u & 7, cell10 = u >> 3;
        int pr = cell10 >> 5, colr = cell10 & 31;
        int cr = r0 + pr - 1;
        uint4v v = {0u, 0u, 0u, 0u};
        if ((unsigned)cr < 32u)
            v = *(const uint4v*)&fmT[((size_t)((y0 + cr) * HFD + x0 + colr)) * 128 + (p >> 2) * 64 + (p & 3) * 16];
        *(uint4v*)(s_a + p * SAPL_M + (pr * 34 + colr + 1) * 16) = v;
    }
    __syncthreads();

#define STEP(S_, BU, BP) do {                                                              \
    const int s_ = (S_);                                                                   \
    const int c_ = s_ / 9, r_ = s_ % 9;                                                    \
    const int kx_ = r_ / 3, ky_ = r_ % 3;                                                  \
    V32 a2[2];                                                                             \
    _Pragma("unroll")                                                                      \
    for (int f = 0; f < 2; ++f) {                                                          \
        int cell = (2 * w + ky_ + f) * 34 + l31 + kx_;                                     \
        a2[f].q[0] = *(const uint4v*)(s_a + (c_ * 4 + 2 * kh)     * SAPL_M + cell * 16);   \
        a2[f].q[1] = *(const uint4v*)(s_a + (c_ * 4 + 2 * kh + 1) * SAPL_M + cell * 16);   \
    }                                                                                      \
    {                                                                                      \
        int s2 = s_ + 2;                                                                   \
        if (s2 < 18) {                                                                     \
            int c2 = s2 / 9, r2 = s2 % 9;                                                  \
            loadB((r2 % 3) * 3 + r2 / 3, c2, BP);                                          \
        }                                                                                  \
    }                                                                                      \
    _Pragma("unroll")                                                                      \
    for (int mt = 0; mt < 2; ++mt) {                                                       \
        acc[mt][0] = __builtin_amdgcn_mfma_scale_f32_32x32x64_f8f6f4(                      \
            a2[mt].v, BU[0].v, acc[mt][0], 0, 0, 0, 127, 0, 127);                          \
        acc[mt][1] = __builtin_amdgcn_mfma_scale_f32_32x32x64_f8f6f4(                      \
            a2[mt].v, BU[1].v, acc[mt][1], 0, 0, 0, 127, 0, 127);                          \
    }                                                                                      \
} while (0)

    #pragma unroll 1
    for (int gi = 0; gi < 3; ++gi) {
        const int sb = 6 * gi;
        STEP(sb + 0, b0,  b2);
        STEP(sb + 1, b1v, b0);
        STEP(sb + 2, b2,  b1v);
        STEP(sb + 3, b0,  b2);
        STEP(sb + 4, b1v, b0);
        STEP(sb + 5, b2,  b1v);
    }
#undef STEP

    // ---- epilogue: h = acc/64 + b1, relu -> s_h (bf16, 8 planes of 8 oc) ----
    __syncthreads();
    #pragma unroll
    for (int nt = 0; nt < 2; ++nt) {
        float bias = b1[g * 64 + nt * 32 + l31];
        int plane = nt * 4 + (l31 >> 3);
        #pragma unroll
        for (int mt = 0; mt < 2; ++mt) {
            int lr = 2 * w + mt;
            #pragma unroll
            for (int reg = 0; reg < 16; ++reg) {
                int col = (reg & 3) + 8 * (reg >> 2) + 4 * kh;   // C layout: m = crop col
                float hv = fmaxf(fmaf(acc[mt][nt][reg], 0.015625f, bias), 0.0f);
                *(ushort_t*)(smem + plane * PSTR_Q + ((lr * 32 + col) * 8 + (l31 & 7)) * 2) = f2bf(hv);
            }
        }
    }
    __syncthreads();

    // ---- v_tap = h @ W2^T (bf16, K=64 oc over 4 x K16) ----
    floatx16 vacc[2];
    #pragma unroll
    for (int mt = 0; mt < 2; ++mt)
        #pragma unroll
        for (int r = 0; r < 16; ++r) vacc[mt][r] = 0.0f;
    #pragma unroll
    for (int ks = 0; ks < 4; ++ks) {
        short8 bw = *(const short8*)&w2r[l31 * 256 + g * 64 + ks * 16 + kh * 8];
        #pragma unroll
        for (int mt = 0; mt < 2; ++mt) {
            short8 ah = *(const short8*)(smem + (ks * 2 + kh) * PSTR_Q + ((2 * w + mt) * 32 + l31) * 16);
            vacc[mt] = __builtin_amdgcn_mfma_f32_32x32x16_bf16(ah, bw, vacc[mt], 0, 0, 0);
        }
    }

    // ---- scatter v_tap into 10x32 tile (s_log separate), then global atomics ----
    for (int i = t; i < 320; i += 256) s_log[i] = 0.0f;
    __syncthreads();
    if (l31 < 9) {
        int ky = l31 / 3, kx = l31 - ky * 3;
        #pragma unroll
        for (int mt = 0; mt < 2; ++mt) {
            int outr = 2 * w + mt + 2 - ky;       // tile row; R = r0 + outr - 1
            #pragma unroll
            for (int reg = 0; reg < 16; ++reg) {
                int col  = (reg & 3) + 8 * (reg >> 2) + 4 * kh;
                int outc = col + 1 - kx;
                if (outc >= 0 && outc < 32)
                    atomicAdd(&s_log[outr * 32 + outc], vacc[mt][reg]);
            }
        }
    }
    __syncthreads();
    for (int i = t; i < 320; i += 256) {
        int outr = i >> 5, outc = i & 31;
        int R = r0 + outr - 1;
        if ((unsigned)R < 32u)
            atomicAdd(&logits[n * 1024 + R * 32 + outc], s_log[i]);
    }
}

__global__ __launch_bounds__(256) void bce_reduce_kernel(
    const float* __restrict__ logits, const int* __restrict__ seg,
    const int* __restrict__ anchors, const int* __restrict__ labels,
    const int* __restrict__ base_classes, const float* __restrict__ b2,
    float* __restrict__ out)
{
    const int n = blockIdx.x;
    const int t = threadIdx.x;
    const int y0 = anchors[n * 4 + 2];
    const int x0 = anchors[n * 4 + 0];
    const int tgt_cls = base_classes[labels[n]];
    const float bias2 = b2[0];

    float lsum = 0.0f;
    #pragma unroll
    for (int r = 0; r < 4; ++r) {
        int p = t + r * 256;
        int i = p >> 5, j = p & 31;
        float l = logits[n * 1024 + p] + bias2;
        int sv = seg[(size_t)(4 * (y0 + i)) * IMGD + 4 * (x0 + j)];
        float tgt = (sv == tgt_cls) ? 1.0f : 0.0f;
        lsum += fmaxf(l, 0.0f) - l * tgt + log1pf(expf(-fabsf(l)));
    }
    #pragma unroll
    for (int off = 32; off > 0; off >>= 1) lsum += __shfl_down(lsum, off, 64);
    __shared__ float s[4];
    if ((t & 63) == 0) s[t >> 6] = lsum;
    __syncthreads();
    if (t == 0) {
        float tot = s[0] + s[1] + s[2] + s[3];
        const float scale = 1.0f / (1024.0f * (256.0f + 1e-10f));
        atomicAdd(out, tot * scale);
    }
}

extern "C" void kernel_launch(void* const* d_in, const int* in_sizes, int n_in,
                              void* d_out, int out_size, void* d_ws, size_t ws_size,
                              hipStream_t stream) {
    const float* fm           = (const float*)d_in[0];
    const int*   seg          = (const int*)d_in[1];
    const int*   anchors      = (const int*)d_in[2];
    const int*   labels       = (const int*)d_in[3];
    const int*   base_classes = (const int*)d_in[4];
    const float* W1           = (const float*)d_in[5];
    const float* b1           = (const float*)d_in[6];
    const float* W2           = (const float*)d_in[7];
    const float* b2           = (const float*)d_in[8];
    float* out = (float*)d_out;

    float*    logits = (float*)d_ws;
    uchar_t*  w1b    = (uchar_t*)((char*)d_ws + W1R_BYTE_OFF);
    ushort_t* w2r    = (ushort_t*)((char*)d_ws + W2R_BYTE_OFF);
    uchar_t*  fmT    = (uchar_t*)((char*)d_ws + FMT_BYTE_OFF);

    prep_misc<<<1024 + 128 + 1, 256, 0, stream>>>(W1, W2, logits, out, w1b, w2r);
    prep_transpose<<<dim3(10, 320), 256, 0, stream>>>(fm, fmT);
    conv_mfma_kernel<<<4096, 256, 0, stream>>>(anchors, fmT, w1b, w2r, b1, logits);
    bce_reduce_kernel<<<NA, 256, 0, stream>>>(logits, seg, anchors, labels, base_classes, b2, out);
}

// Round 5
// 241.060 us; speedup vs baseline: 2.7131x; 2.7131x over previous
//
#include <hip/hip_runtime.h>

typedef __attribute__((ext_vector_type(8))) short short8;
typedef __attribute__((ext_vector_type(8))) int int8v;
typedef __attribute__((ext_vector_type(16))) float floatx16;
typedef __attribute__((ext_vector_type(4))) unsigned int uint4v;
typedef unsigned short ushort_t;
typedef unsigned int uint_t;
typedef unsigned char uchar_t;

#define NA   256
#define CIN  128
#define HFD  320
#define FMPX (HFD*HFD)
#define IMGD 1280

// ws layout (bytes):
//   [0, 1MB)              logits f32 (NA*1024)
//   [1MB, +294912)        w1b fp8  [tap][g][nt][c][lane64][32B]  (coalesced B-frag layout), scaled x64
//   [+294912, +311296)    w2r bf16 [32 krow][256 oc]
//   [2MB, 2MB+13107200)   fmT fp8  [320 y][320 x][128 c]
#define W1R_BYTE_OFF (1u<<20)
#define W2R_BYTE_OFF ((1u<<20) + 9*256*128)
#define FMT_BYTE_OFF (2u<<20)

#define SAPL_Q 5440               // A sub-plane bytes: 340 cells (10 rows x 34 cols) * 16
#define PSTR_Q 4112               // bytes per oc-octet plane of s_h: 8*32*16 + 16 pad

union V32 { int8v v; uint4v q[2]; };

__device__ __forceinline__ ushort_t f2bf(float v) {
    uint_t u = __float_as_uint(v);
    return (ushort_t)((u + 0x8000u) >> 16);
}
__device__ __forceinline__ uchar_t f2fp8(float v) {
    int r = __builtin_amdgcn_cvt_pk_fp8_f32(v, 0.0f, 0, false);
    return (uchar_t)(r & 0xff);
}

__global__ __launch_bounds__(256) void prep_misc(
    const float* __restrict__ W1, const float* __restrict__ W2,
    float* __restrict__ logits, float* __restrict__ out,
    uchar_t* __restrict__ w1b, ushort_t* __restrict__ w2r)
{
    const int b = blockIdx.x, t = threadIdx.x;
    if (b < 1024) {
        logits[b * 256 + t] = 0.0f;
    } else if (b < 1024 + 128) {
        int e = (b - 1024) * 256 + t;
        int oc = e >> 7, cin = e & 127;
        int g = oc >> 6, nt = (oc >> 5) & 1, lv = oc & 31;
        int c = cin >> 6, kh = (cin >> 5) & 1, j = cin & 31;
        #pragma unroll
        for (int tap = 0; tap < 9; ++tap) {
            int idx = (((((tap * 4 + g) * 2 + nt) * 2 + c) * 64) + kh * 32 + lv) * 32 + j;
            w1b[idx] = f2fp8(W1[(oc * 128 + cin) * 9 + tap] * 64.0f);
        }
    } else {
        #pragma unroll
        for (int i = 0; i < 32; ++i) {
            int e = i * 256 + t;
            int nrow = e >> 8, oc = e & 255;
            w2r[nrow * 256 + oc] = f2bf(nrow < 9 ? W2[oc * 9 + nrow] : 0.0f);
        }
        if (t == 0) out[0] = 0.0f;
    }
}

// fm f32 [c][y][x] -> fmT fp8 [y][x][c]
__global__ __launch_bounds__(256) void prep_transpose(
    const float* __restrict__ fm, uchar_t* __restrict__ fmT)
{
    __shared__ uchar_t s[32 * 144];
    const int t = threadIdx.x;
    const int y = blockIdx.y, x0b = blockIdx.x * 32;
    #pragma unroll
    for (int i = 0; i < 16; ++i) {
        int e = t + 256 * i;
        int c = e >> 5, xo = e & 31;
        s[xo * 144 + c] = f2fp8(fm[(size_t)c * FMPX + y * HFD + x0b + xo]);
    }
    __syncthreads();
    {
        int xo = t >> 3, cg = t & 7;
        uint4v v = *(const uint4v*)&s[xo * 144 + cg * 16];
        *(uint4v*)&fmT[((size_t)(y * HFD + x0b + xo)) * 128 + cg * 16] = v;
    }
}

// Block = (anchor, 8-row quarter, 64-oc group); grid 4096, XCD-swizzled.
// STRUCTURE = R3 (the proven spill-free schedule: rolled tap loop, statically-named
// 1-deep prefetch ping, lambda loaders) + ONE change: A-fragment register double-buffer
// (acur/anxt) so each step's MFMAs consume ds_reads issued a full step earlier --
// compiler emits lgkmcnt(4), hiding the ~150-250cy LDS latency under the MFMAs.
// SPILL HISTORY (do not regress): any structure that widens the scheduler's load window
// spills catastrophically (R1 unrolled taps: 450 MB scratch; R2 capped: 253 MB; R4
// 6-step macro body w/ runtime step base: 1.7 GB). Keep: rolled #pragma unroll 1 loop,
// static buffer names, unconditional-ish loads, (256,3) cap (live set ~140 < 168;
// (256,4)'s cap 128 < 140 WILL spill).
// Accumulation order (c, kx, ky) preserved exactly -> bit-identical conv results.
// B operand from L2 (w1b pre-permuted: one coalesced 2048-B wave read per frag).
__global__ __launch_bounds__(256, 3) void conv_mfma_kernel(
    const int* __restrict__ anchors, const uchar_t* __restrict__ fmT,
    const uchar_t* __restrict__ w1b, const ushort_t* __restrict__ w2r,
    const float* __restrict__ b1, float* __restrict__ logits)
{
    const int id   = blockIdx.x;
    const int xcd  = id & 7, sid = id >> 3;
    const int n    = xcd * 32 + (sid >> 4);
    const int rem  = sid & 15;
    const int q    = rem >> 2;
    const int g    = rem & 3;

    const int t    = threadIdx.x;
    const int w    = t >> 6;
    const int lane = t & 63;
    const int l31  = lane & 31;
    const int kh   = lane >> 5;

    const int x0 = anchors[n * 4 + 0];
    const int y0 = anchors[n * 4 + 2];
    const int r0 = q * 8;

    __shared__ __align__(16) char smem[8 * PSTR_Q];   // 32896 B: s_a(21760) / s_h / s_log union
    char* s_a = smem;

    // zero col pads (cols 0 & 33 of 10 rows, 4 sub-planes) — persist across both chunks
    if (t < 80) {
        int sub = t & 3, k = t >> 2;
        int pr = k >> 1, col = (k & 1) * 33;
        uint4v z = {0u, 0u, 0u, 0u};
        *(uint4v*)(s_a + sub * SAPL_Q + (pr * 34 + col) * 16) = z;
    }

    floatx16 acc[2][2];
    #pragma unroll
    for (int mt = 0; mt < 2; ++mt)
        #pragma unroll
        for (int nt = 0; nt < 2; ++nt)
            #pragma unroll
            for (int r = 0; r < 16; ++r) acc[mt][nt][r] = 0.0f;

    // B-fragment loader: tap in [0,9), cc = cin chunk
    auto loadB = [&](int tap, int cc, V32* b) {
        #pragma unroll
        for (int nt = 0; nt < 2; ++nt) {
            const uchar_t* bp = w1b + ((((tap * 4 + g) * 2 + nt) * 2 + cc) << 11) + lane * 32;
            b[nt].q[0] = *(const uint4v*)(bp);
            b[nt].q[1] = *(const uint4v*)(bp + 16);
        }
    };
    // A-fragment loader from LDS
    auto loadA = [&](int kx, int ky, V32* a) {
        #pragma unroll
        for (int f = 0; f < 2; ++f) {
            int cell = (2 * w + ky + f) * 34 + l31 + kx;
            a[f].q[0] = *(const uint4v*)(s_a + (2 * kh)     * SAPL_Q + cell * 16);
            a[f].q[1] = *(const uint4v*)(s_a + (2 * kh + 1) * SAPL_Q + cell * 16);
        }
    };

    V32 bcur[2], bnxt[2];
    loadB(0, 0, bcur);    // tap for s=0 (kx=0,ky=0) of chunk 0

    for (int c = 0; c < 2; ++c) {
        __syncthreads();   // c0: pad zeros visible; c1: all waves done reading chunk0
        // ---- stage A: 10 rows x 32 real cols x 4 subs = 1280 uint4 units (5 iters) ----
        // invalid halo rows (cr outside [0,32)) are written as zeros (conv SAME pad)
        #pragma unroll
        for (int j = 0; j < 5; ++j) {
            int u = t + 256 * j;
            int pr = u >> 7, rr = u & 127;
            int cell = rr >> 2, sub = rr & 3;
            int cr = r0 + pr - 1;
            uint4v v = {0u, 0u, 0u, 0u};
            if ((unsigned)cr < 32u)
                v = *(const uint4v*)&fmT[((size_t)((y0 + cr) * HFD + x0 + cell)) * 128 + c * 64 + sub * 16];
            *(uint4v*)(s_a + sub * SAPL_Q + (pr * 34 + cell + 1) * 16) = v;
        }
        __syncthreads();

        V32 acur[2], anxt[2];
        loadA(0, 0, acur);   // prologue for s=0 (only chunk-start lgkm exposure)

        // ---- MFMA: rolled tap loop; A and B both 1-step register-prefetched ----
        #pragma unroll 1
        for (int s = 0; s < 9; ++s) {
            const int s2 = s + 1;
            // prefetch B for next tap (crosses into chunk 1 at the end of chunk 0)
            if (s2 < 9)      loadB((s2 - (s2 / 3) * 3) * 3 + s2 / 3, c, bnxt);
            else if (c == 0) loadB(0, 1, bnxt);
            // prefetch A-frags for next step (same chunk only)
            if (s2 < 9)      loadA(s2 / 3, s2 - (s2 / 3) * 3, anxt);
            // MFMAs consume acur (ds_reads issued last step -> lgkmcnt(4), ~free)
            #pragma unroll
            for (int mt = 0; mt < 2; ++mt) {
                acc[mt][0] = __builtin_amdgcn_mfma_scale_f32_32x32x64_f8f6f4(
                    acur[mt].v, bcur[0].v, acc[mt][0], 0, 0, 0, 127, 0, 127);
                acc[mt][1] = __builtin_amdgcn_mfma_scale_f32_32x32x64_f8f6f4(
                    acur[mt].v, bcur[1].v, acc[mt][1], 0, 0, 0, 127, 0, 127);
            }
            // rotate (explicit, statically named)
            bcur[0] = bnxt[0];
            bcur[1] = bnxt[1];
            if (s2 < 9) {
                acur[0] = anxt[0];
                acur[1] = anxt[1];
            }
        }
    }

    // ---- epilogue: h = acc/64 + b1, relu -> s_h (bf16, 8 planes of 8 oc) ----
    __syncthreads();
    #pragma unroll
    for (int nt = 0; nt < 2; ++nt) {
        float bias = b1[g * 64 + nt * 32 + l31];
        int plane = nt * 4 + (l31 >> 3);
        #pragma unroll
        for (int mt = 0; mt < 2; ++mt) {
            int lr = 2 * w + mt;
            #pragma unroll
            for (int reg = 0; reg < 16; ++reg) {
                int col = (reg & 3) + 8 * (reg >> 2) + 4 * kh;   // C layout: m = crop col
                float hv = fmaxf(fmaf(acc[mt][nt][reg], 0.015625f, bias), 0.0f);
                *(ushort_t*)(smem + plane * PSTR_Q + ((lr * 32 + col) * 8 + (l31 & 7)) * 2) = f2bf(hv);
            }
        }
    }
    __syncthreads();

    // ---- v_tap = h @ W2^T (bf16, K=64 oc over 4 x K16) ----
    floatx16 vacc[2];
    #pragma unroll
    for (int mt = 0; mt < 2; ++mt)
        #pragma unroll
        for (int r = 0; r < 16; ++r) vacc[mt][r] = 0.0f;
    #pragma unroll
    for (int ks = 0; ks < 4; ++ks) {
        short8 bw = *(const short8*)&w2r[l31 * 256 + g * 64 + ks * 16 + kh * 8];
        #pragma unroll
        for (int mt = 0; mt < 2; ++mt) {
            short8 ah = *(const short8*)(smem + (ks * 2 + kh) * PSTR_Q + ((2 * w + mt) * 32 + l31) * 16);
            vacc[mt] = __builtin_amdgcn_mfma_f32_32x32x16_bf16(ah, bw, vacc[mt], 0, 0, 0);
        }
    }

    // ---- scatter v_tap into 10x32 tile (s_h now dead -> union), then global atomics ----
    __syncthreads();
    float* s_log = (float*)smem;
    for (int i = t; i < 320; i += 256) s_log[i] = 0.0f;
    __syncthreads();
    if (l31 < 9) {
        int ky = l31 / 3, kx = l31 - ky * 3;
        #pragma unroll
        for (int mt = 0; mt < 2; ++mt) {
            int outr = 2 * w + mt + 2 - ky;       // tile row; R = r0 + outr - 1
            #pragma unroll
            for (int reg = 0; reg < 16; ++reg) {
                int col  = (reg & 3) + 8 * (reg >> 2) + 4 * kh;
                int outc = col + 1 - kx;
                if (outc >= 0 && outc < 32)
                    atomicAdd(&s_log[outr * 32 + outc], vacc[mt][reg]);
            }
        }
    }
    __syncthreads();
    for (int i = t; i < 320; i += 256) {
        int outr = i >> 5, outc = i & 31;
        int R = r0 + outr - 1;
        if ((unsigned)R < 32u)
            atomicAdd(&logits[n * 1024 + R * 32 + outc], s_log[i]);
    }
}

__global__ __launch_bounds__(256) void bce_reduce_kernel(
    const float* __restrict__ logits, const int* __restrict__ seg,
    const int* __restrict__ anchors, const int* __restrict__ labels,
    const int* __restrict__ base_classes, const float* __restrict__ b2,
    float* __restrict__ out)
{
    const int n = blockIdx.x;
    const int t = threadIdx.x;
    const int y0 = anchors[n * 4 + 2];
    const int x0 = anchors[n * 4 + 0];
    const int tgt_cls = base_classes[labels[n]];
    const float bias2 = b2[0];

    float lsum = 0.0f;
    #pragma unroll
    for (int r = 0; r < 4; ++r) {
        int p = t + r * 256;
        int i = p >> 5, j = p & 31;
        float l = logits[n * 1024 + p] + bias2;
        int sv = seg[(size_t)(4 * (y0 + i)) * IMGD + 4 * (x0 + j)];
        float tgt = (sv == tgt_cls) ? 1.0f : 0.0f;
        lsum += fmaxf(l, 0.0f) - l * tgt + log1pf(expf(-fabsf(l)));
    }
    #pragma unroll
    for (int off = 32; off > 0; off >>= 1) lsum += __shfl_down(lsum, off, 64);
    __shared__ float s[4];
    if ((t & 63) == 0) s[t >> 6] = lsum;
    __syncthreads();
    if (t == 0) {
        float tot = s[0] + s[1] + s[2] + s[3];
        const float scale = 1.0f / (1024.0f * (256.0f + 1e-10f));
        atomicAdd(out, tot * scale);
    }
}

extern "C" void kernel_launch(void* const* d_in, const int* in_sizes, int n_in,
                              void* d_out, int out_size, void* d_ws, size_t ws_size,
                              hipStream_t stream) {
    const float* fm           = (const float*)d_in[0];
    const int*   seg          = (const int*)d_in[1];
    const int*   anchors      = (const int*)d_in[2];
    const int*   labels       = (const int*)d_in[3];
    const int*   base_classes = (const int*)d_in[4];
    const float* W1           = (const float*)d_in[5];
    const float* b1           = (const float*)d_in[6];
    const float* W2           = (const float*)d_in[7];
    const float* b2           = (const float*)d_in[8];
    float* out = (float*)d_out;

    float*    logits = (float*)d_ws;
    uchar_t*  w1b    = (uchar_t*)((char*)d_ws + W1R_BYTE_OFF);
    ushort_t* w2r    = (ushort_t*)((char*)d_ws + W2R_BYTE_OFF);
    uchar_t*  fmT    = (uchar_t*)((char*)d_ws + FMT_BYTE_OFF);

    prep_misc<<<1024 + 128 + 1, 256, 0, stream>>>(W1, W2, logits, out, w1b, w2r);
    prep_transpose<<<dim3(10, 320), 256, 0, stream>>>(fm, fmT);
    conv_mfma_kernel<<<4096, 256, 0, stream>>>(anchors, fmT, w1b, w2r, b1, logits);
    bce_reduce_kernel<<<NA, 256, 0, stream>>>(logits, seg, anchors, labels, base_classes, b2, out);
}

// Round 6
// 226.559 us; speedup vs baseline: 2.8868x; 1.0640x over previous
//
#include <hip/hip_runtime.h>

typedef __attribute__((ext_vector_type(8))) short short8;
typedef __attribute__((ext_vector_type(8))) int int8v;
typedef __attribute__((ext_vector_type(16))) float floatx16;
typedef __attribute__((ext_vector_type(4))) unsigned int uint4v;
typedef unsigned short ushort_t;
typedef unsigned int uint_t;
typedef unsigned char uchar_t;

#define NA   256
#define CIN  128
#define HFD  320
#define FMPX (HFD*HFD)
#define IMGD 1280

// ws layout (bytes):
//   [0, 1MB)              logits f32 (NA*1024)
//   [1MB, +294912)        w1b fp8  [tap][g][nt][c][lane64][32B]  (coalesced B-frag layout), scaled x64
//   [+294912, +311296)    w2r bf16 [32 krow][256 oc]
//   [2MB, 2MB+13107200)   fmT fp8  [320 y][320 x][128 c]
#define W1R_BYTE_OFF (1u<<20)
#define W2R_BYTE_OFF ((1u<<20) + 9*256*128)
#define FMT_BYTE_OFF (2u<<20)

#define SAPL_Q 5440               // A sub-plane bytes: 340 cells (10 rows x 34 cols) * 16
#define PSTR_Q 4112               // bytes per oc-octet plane of s_h: 8*32*16 + 16 pad

union V32 { int8v v; uint4v q[2]; };

__device__ __forceinline__ ushort_t f2bf(float v) {
    uint_t u = __float_as_uint(v);
    return (ushort_t)((u + 0x8000u) >> 16);
}
__device__ __forceinline__ uchar_t f2fp8(float v) {
    int r = __builtin_amdgcn_cvt_pk_fp8_f32(v, 0.0f, 0, false);
    return (uchar_t)(r & 0xff);
}

__global__ __launch_bounds__(256) void prep_misc(
    const float* __restrict__ W1, const float* __restrict__ W2,
    float* __restrict__ logits, float* __restrict__ out,
    uchar_t* __restrict__ w1b, ushort_t* __restrict__ w2r)
{
    const int b = blockIdx.x, t = threadIdx.x;
    if (b < 1024) {
        logits[b * 256 + t] = 0.0f;
    } else if (b < 1024 + 128) {
        int e = (b - 1024) * 256 + t;
        int oc = e >> 7, cin = e & 127;
        int g = oc >> 6, nt = (oc >> 5) & 1, lv = oc & 31;
        int c = cin >> 6, kh = (cin >> 5) & 1, j = cin & 31;
        #pragma unroll
        for (int tap = 0; tap < 9; ++tap) {
            int idx = (((((tap * 4 + g) * 2 + nt) * 2 + c) * 64) + kh * 32 + lv) * 32 + j;
            w1b[idx] = f2fp8(W1[(oc * 128 + cin) * 9 + tap] * 64.0f);
        }
    } else {
        #pragma unroll
        for (int i = 0; i < 32; ++i) {
            int e = i * 256 + t;
            int nrow = e >> 8, oc = e & 255;
            w2r[nrow * 256 + oc] = f2bf(nrow < 9 ? W2[oc * 9 + nrow] : 0.0f);
        }
        if (t == 0) out[0] = 0.0f;
    }
}

// fm f32 [c][y][x] -> fmT fp8 [y][x][c]
__global__ __launch_bounds__(256) void prep_transpose(
    const float* __restrict__ fm, uchar_t* __restrict__ fmT)
{
    __shared__ uchar_t s[32 * 144];
    const int t = threadIdx.x;
    const int y = blockIdx.y, x0b = blockIdx.x * 32;
    #pragma unroll
    for (int i = 0; i < 16; ++i) {
        int e = t + 256 * i;
        int c = e >> 5, xo = e & 31;
        s[xo * 144 + c] = f2fp8(fm[(size_t)c * FMPX + y * HFD + x0b + xo]);
    }
    __syncthreads();
    {
        int xo = t >> 3, cg = t & 7;
        uint4v v = *(const uint4v*)&s[xo * 144 + cg * 16];
        *(uint4v*)&fmT[((size_t)(y * HFD + x0b + xo)) * 128 + cg * 16] = v;
    }
}

// Block = (anchor, 8-row quarter, 64-oc group); grid 4096, XCD-swizzled.
// R6 main loop: (c rolled, gi=kx rolled #pragma unroll 1, ky=k UNROLLED 0..2).
//  - s%3==k compile-time -> step k uses buffer bb_k STATICALLY (no rotate movs);
//    prefetch at k targets bb_{(k+2)%3} = distance-2 L2 cover (~550+ cy) with exactly
//    3 live buffers bounded by WAR; all prefetch loads UNCONDITIONAL (chunk-boundary
//    clamps to dead reloads -- no phi merges).
//  - ky compile-time -> 4 shared A-frags a0..a3 per gi (8 ds_read_b128 off ONE address
//    + immediate offsets); k uses (a_k, a_{k+1}). 1 lgkm exposure per 12 MFMAs.
//  - tap/address math affine in gi: no div/mod, no per-step address recompute.
// SPILL HISTORY (do not regress): window-widening spills (R1 450MB / R2 253MB / R4 1.7GB:
// unrolled-step bodies w/ runtime step index + conditional buffer writes). R5's A-dbuf +
// rotate movs: -12% + 18MB spill. Keep: static buffer names, unconditional loads,
// rolled gi, (256,3). Live set ~159 regs < 170 cap. ((256,4) cap 128 WILL spill.)
// Accumulation order (c, kx, ky) preserved exactly -> bit-identical conv results.
__global__ __launch_bounds__(256, 3) void conv_mfma_kernel(
    const int* __restrict__ anchors, const uchar_t* __restrict__ fmT,
    const uchar_t* __restrict__ w1b, const ushort_t* __restrict__ w2r,
    const float* __restrict__ b1, float* __restrict__ logits)
{
    const int id   = blockIdx.x;
    const int xcd  = id & 7, sid = id >> 3;
    const int n    = xcd * 32 + (sid >> 4);
    const int rem  = sid & 15;
    const int q    = rem >> 2;
    const int g    = rem & 3;

    const int t    = threadIdx.x;
    const int w    = t >> 6;
    const int lane = t & 63;
    const int l31  = lane & 31;
    const int kh   = lane >> 5;

    const int x0 = anchors[n * 4 + 0];
    const int y0 = anchors[n * 4 + 2];
    const int r0 = q * 8;

    __shared__ __align__(16) char smem[8 * PSTR_Q];   // 32896 B: s_a(21760) / s_h / s_log union
    char* s_a = smem;

    // zero col pads (cols 0 & 33 of 10 rows, 4 sub-planes) — persist across both chunks
    if (t < 80) {
        int sub = t & 3, k = t >> 2;
        int pr = k >> 1, col = (k & 1) * 33;
        uint4v z = {0u, 0u, 0u, 0u};
        *(uint4v*)(s_a + sub * SAPL_Q + (pr * 34 + col) * 16) = z;
    }

    floatx16 acc[2][2];
    #pragma unroll
    for (int mt = 0; mt < 2; ++mt)
        #pragma unroll
        for (int nt = 0; nt < 2; ++nt)
            #pragma unroll
            for (int r = 0; r < 16; ++r) acc[mt][nt][r] = 0.0f;

    // B-fragment loader: tap in [0,9), cc = cin chunk
    auto loadB = [&](int tap, int cc, V32* b) {
        #pragma unroll
        for (int nt = 0; nt < 2; ++nt) {
            const uchar_t* bp = w1b + ((((tap * 4 + g) * 2 + nt) * 2 + cc) << 11) + lane * 32;
            b[nt].q[0] = *(const uint4v*)(bp);
            b[nt].q[1] = *(const uint4v*)(bp + 16);
        }
    };

#define MF4(AL, AH, BB)                                                                   \
    acc[0][0] = __builtin_amdgcn_mfma_scale_f32_32x32x64_f8f6f4(                          \
        (AL).v, (BB)[0].v, acc[0][0], 0, 0, 0, 127, 0, 127);                              \
    acc[0][1] = __builtin_amdgcn_mfma_scale_f32_32x32x64_f8f6f4(                          \
        (AL).v, (BB)[1].v, acc[0][1], 0, 0, 0, 127, 0, 127);                              \
    acc[1][0] = __builtin_amdgcn_mfma_scale_f32_32x32x64_f8f6f4(                          \
        (AH).v, (BB)[0].v, acc[1][0], 0, 0, 0, 127, 0, 127);                              \
    acc[1][1] = __builtin_amdgcn_mfma_scale_f32_32x32x64_f8f6f4(                          \
        (AH).v, (BB)[1].v, acc[1][1], 0, 0, 0, 127, 0, 127);

    V32 bb0[2], bb1[2], bb2[2];
    // prime: s=0 -> (kx=0,ky=0) tap 0; s=1 -> (kx=0,ky=1) tap 3; both chunk 0
    loadB(0, 0, bb0);
    loadB(3, 0, bb1);

    #pragma unroll 1
    for (int c = 0; c < 2; ++c) {
        __syncthreads();   // c0: pad zeros visible; c1: all waves done reading chunk0
        // ---- stage A: 10 rows x 32 real cols x 4 subs = 1280 uint4 units (5 iters) ----
        // invalid halo rows (cr outside [0,32)) are written as zeros (conv SAME pad)
        #pragma unroll
        for (int j = 0; j < 5; ++j) {
            int u = t + 256 * j;
            int pr = u >> 7, rr = u & 127;
            int cell = rr >> 2, sub = rr & 3;
            int cr = r0 + pr - 1;
            uint4v v = {0u, 0u, 0u, 0u};
            if ((unsigned)cr < 32u)
                v = *(const uint4v*)&fmT[((size_t)((y0 + cr) * HFD + x0 + cell)) * 128 + c * 64 + sub * 16];
            *(uint4v*)(s_a + sub * SAPL_Q + (pr * 34 + cell + 1) * 16) = v;
        }
        __syncthreads();

        // ---- MFMA: gi = kx rolled; ky unrolled with static buffer naming ----
        #pragma unroll 1
        for (int gi = 0; gi < 3; ++gi) {
            // 4 shared A-frags: rows 2w..2w+3 at col offset gi (one addr + imm offsets)
            V32 fa0, fa1, fa2, fa3;
            {
                const char* ap = s_a + (2 * kh) * SAPL_Q + ((2 * w) * 34 + l31 + gi) * 16;
                fa0.q[0] = *(const uint4v*)(ap);
                fa0.q[1] = *(const uint4v*)(ap + SAPL_Q);
                fa1.q[0] = *(const uint4v*)(ap + 544);
                fa1.q[1] = *(const uint4v*)(ap + SAPL_Q + 544);
                fa2.q[0] = *(const uint4v*)(ap + 1088);
                fa2.q[1] = *(const uint4v*)(ap + SAPL_Q + 1088);
                fa3.q[0] = *(const uint4v*)(ap + 1632);
                fa3.q[1] = *(const uint4v*)(ap + SAPL_Q + 1632);
            }
            // boundary-aware prefetch taps (affine in gi; unconditional loads)
            const int last = (gi == 2);
            const int tapk1 = last ? 0 : gi + 1;      // next step (gi+1,0) / next chunk (0,0)
            const int tapk2 = last ? 3 : gi + 4;      // next step (gi+1,1) / next chunk (0,1)
            const int ccn   = last ? 1 : c;           // c==1,gi==2: dead reload of cc=1 (harmless)

            // k=0: consume bb0; prefetch bb2 for (gi, k=2), tap 6+gi
            loadB(6 + gi, c, bb2);
            MF4(fa0, fa1, bb0)
            // k=1: consume bb1; prefetch bb0 for (gi+1, k=0)
            loadB(tapk1, ccn, bb0);
            MF4(fa1, fa2, bb1)
            // k=2: consume bb2; prefetch bb1 for (gi+1, k=1)
            loadB(tapk2, ccn, bb1);
            MF4(fa2, fa3, bb2)
        }
    }
#undef MF4

    // ---- epilogue: h = acc/64 + b1, relu -> s_h (bf16, 8 planes of 8 oc) ----
    __syncthreads();
    #pragma unroll
    for (int nt = 0; nt < 2; ++nt) {
        float bias = b1[g * 64 + nt * 32 + l31];
        int plane = nt * 4 + (l31 >> 3);
        #pragma unroll
        for (int mt = 0; mt < 2; ++mt) {
            int lr = 2 * w + mt;
            #pragma unroll
            for (int reg = 0; reg < 16; ++reg) {
                int col = (reg & 3) + 8 * (reg >> 2) + 4 * kh;   // C layout: m = crop col
                float hv = fmaxf(fmaf(acc[mt][nt][reg], 0.015625f, bias), 0.0f);
                *(ushort_t*)(smem + plane * PSTR_Q + ((lr * 32 + col) * 8 + (l31 & 7)) * 2) = f2bf(hv);
            }
        }
    }
    __syncthreads();

    // ---- v_tap = h @ W2^T (bf16, K=64 oc over 4 x K16) ----
    floatx16 vacc[2];
    #pragma unroll
    for (int mt = 0; mt < 2; ++mt)
        #pragma unroll
        for (int r = 0; r < 16; ++r) vacc[mt][r] = 0.0f;
    #pragma unroll
    for (int ks = 0; ks < 4; ++ks) {
        short8 bw = *(const short8*)&w2r[l31 * 256 + g * 64 + ks * 16 + kh * 8];
        #pragma unroll
        for (int mt = 0; mt < 2; ++mt) {
            short8 ah = *(const short8*)(smem + (ks * 2 + kh) * PSTR_Q + ((2 * w + mt) * 32 + l31) * 16);
            vacc[mt] = __builtin_amdgcn_mfma_f32_32x32x16_bf16(ah, bw, vacc[mt], 0, 0, 0);
        }
    }

    // ---- scatter v_tap into 10x32 tile (s_h now dead -> union), then global atomics ----
    __syncthreads();
    float* s_log = (float*)smem;
    for (int i = t; i < 320; i += 256) s_log[i] = 0.0f;
    __syncthreads();
    if (l31 < 9) {
        int ky = l31 / 3, kx = l31 - ky * 3;
        #pragma unroll
        for (int mt = 0; mt < 2; ++mt) {
            int outr = 2 * w + mt + 2 - ky;       // tile row; R = r0 + outr - 1
            #pragma unroll
            for (int reg = 0; reg < 16; ++reg) {
                int col  = (reg & 3) + 8 * (reg >> 2) + 4 * kh;
                int outc = col + 1 - kx;
                if (outc >= 0 && outc < 32)
                    atomicAdd(&s_log[outr * 32 + outc], vacc[mt][reg]);
            }
        }
    }
    __syncthreads();
    for (int i = t; i < 320; i += 256) {
        int outr = i >> 5, outc = i & 31;
        int R = r0 + outr - 1;
        if ((unsigned)R < 32u)
            atomicAdd(&logits[n * 1024 + R * 32 + outc], s_log[i]);
    }
}

__global__ __launch_bounds__(256) void bce_reduce_kernel(
    const float* __restrict__ logits, const int* __restrict__ seg,
    const int* __restrict__ anchors, const int* __restrict__ labels,
    const int* __restrict__ base_classes, const float* __restrict__ b2,
    float* __restrict__ out)
{
    const int n = blockIdx.x;
    const int t = threadIdx.x;
    const int y0 = anchors[n * 4 + 2];
    const int x0 = anchors[n * 4 + 0];
    const int tgt_cls = base_classes[labels[n]];
    const float bias2 = b2[0];

    float lsum = 0.0f;
    #pragma unroll
    for (int r = 0; r < 4; ++r) {
        int p = t + r * 256;
        int i = p >> 5, j = p & 31;
        float l = logits[n * 1024 + p] + bias2;
        int sv = seg[(size_t)(4 * (y0 + i)) * IMGD + 4 * (x0 + j)];
        float tgt = (sv == tgt_cls) ? 1.0f : 0.0f;
        lsum += fmaxf(l, 0.0f) - l * tgt + log1pf(expf(-fabsf(l)));
    }
    #pragma unroll
    for (int off = 32; off > 0; off >>= 1) lsum += __shfl_down(lsum, off, 64);
    __shared__ float s[4];
    if ((t & 63) == 0) s[t >> 6] = lsum;
    __syncthreads();
    if (t == 0) {
        float tot = s[0] + s[1] + s[2] + s[3];
        const float scale = 1.0f / (1024.0f * (256.0f + 1e-10f));
        atomicAdd(out, tot * scale);
    }
}

extern "C" void kernel_launch(void* const* d_in, const int* in_sizes, int n_in,
                              void* d_out, int out_size, void* d_ws, size_t ws_size,
                              hipStream_t stream) {
    const float* fm           = (const float*)d_in[0];
    const int*   seg          = (const int*)d_in[1];
    const int*   anchors      = (const int*)d_in[2];
    const int*   labels       = (const int*)d_in[3];
    const int*   base_classes = (const int*)d_in[4];
    const float* W1           = (const float*)d_in[5];
    const float* b1           = (const float*)d_in[6];
    const float* W2           = (const float*)d_in[7];
    const float* b2           = (const float*)d_in[8];
    float* out = (float*)d_out;

    float*    logits = (float*)d_ws;
    uchar_t*  w1b    = (uchar_t*)((char*)d_ws + W1R_BYTE_OFF);
    ushort_t* w2r    = (ushort_t*)((char*)d_ws + W2R_BYTE_OFF);
    uchar_t*  fmT    = (uchar_t*)((char*)d_ws + FMT_BYTE_OFF);

    prep_misc<<<1024 + 128 + 1, 256, 0, stream>>>(W1, W2, logits, out, w1b, w2r);
    prep_transpose<<<dim3(10, 320), 256, 0, stream>>>(fm, fmT);
    conv_mfma_kernel<<<4096, 256, 0, stream>>>(anchors, fmT, w1b, w2r, b1, logits);
    bce_reduce_kernel<<<NA, 256, 0, stream>>>(logits, seg, anchors, labels, base_classes, b2, out);
}